// Round 1
// baseline (777.936 us; speedup 1.0000x reference)
//
#include <hip/hip_runtime.h>

#define NN 1024
#define CC 64
#define BB 2

typedef unsigned long long ull;

__device__ __forceinline__ float wsum(float v){
  #pragma unroll
  for (int o=32;o;o>>=1) v += __shfl_xor(v,o);
  return v;
}
__device__ __forceinline__ float wmaxr(float v){
  #pragma unroll
  for (int o=32;o;o>>=1) v = fmaxf(v, __shfl_xor(v,o));
  return v;
}
__device__ __forceinline__ float wminr(float v){
  #pragma unroll
  for (int o=32;o;o>>=1) v = fminf(v, __shfl_xor(v,o));
  return v;
}

// ---------------- zero init ----------------
__global__ void kz(float* __restrict__ out, double* __restrict__ sums){
  int i = blockIdx.x*256 + threadIdx.x;
  if (i < BB*CC*NN) out[i] = 0.0f;
  if (i < 36) sums[i] = 0.0;
}

// ---------------- K0a: transpose x[b][c][n] -> f[s][b][n][c] ----------------
__global__ __launch_bounds__(256)
void k0a(const float* __restrict__ x1, const float* __restrict__ x2, const float* __restrict__ x3,
         float* __restrict__ f){
  int bid = blockIdx.x;
  int tile = bid & 15;        // 16 tiles of 64 i
  int b = (bid >> 4) & 1;
  int s = bid >> 5;
  const float* x = (s==0)?x1:((s==1)?x2:x3);
  __shared__ float lds[64][65];
  int i0 = tile*64;
  for (int idx = threadIdx.x; idx < 4096; idx += 256){
    int c = idx >> 6, ii = idx & 63;
    lds[c][ii] = x[(size_t)(b*CC + c)*NN + i0 + ii];
  }
  __syncthreads();
  for (int idx = threadIdx.x; idx < 4096; idx += 256){
    int ii = idx >> 6, c = idx & 63;
    f[((size_t)(s*BB + b)*NN + i0 + ii)*CC + c] = lds[c][ii];
  }
}

// ---------------- K0b: norms, fnT, p, pT ----------------
__global__ __launch_bounds__(256)
void k0b(const float* __restrict__ f,
         const float* __restrict__ w1, const float* __restrict__ b1,
         const float* __restrict__ w2, const float* __restrict__ b2,
         const float* __restrict__ w3, const float* __restrict__ b3,
         float* __restrict__ p, float* __restrict__ pT,
         float* __restrict__ fnT, float* __restrict__ nrm2g){
  int bid = blockIdx.x;
  int chunk = bid & 63;       // 64 chunks of 16 rows
  int b = (bid >> 6) & 1;
  int s = bid >> 7;
  const float* w = (s==0)?w1:((s==1)?w2:w3);
  const float* bias = (s==0)?b1:((s==1)?b2:b3);
  __shared__ float wl[64][65];
  __shared__ float fr[16][65];
  __shared__ float n2[16];
  int i0 = chunk*16;
  int t = threadIdx.x;
  for (int idx = t; idx < 4096; idx += 256){
    int o = idx >> 6, c = idx & 63;
    wl[o][c] = w[idx];
  }
  for (int idx = t; idx < 1024; idx += 256){
    int rr = idx >> 6, c = idx & 63;
    fr[rr][c] = f[((size_t)(s*BB + b)*NN + i0 + rr)*CC + c];
  }
  __syncthreads();
  {
    int r = t >> 4, l = t & 15;
    float pv = 0.f;
    for (int c = l; c < 64; c += 16) pv += fr[r][c]*fr[r][c];
    #pragma unroll
    for (int o=8;o;o>>=1) pv += __shfl_down(pv, o, 16);
    if (l == 0) n2[r] = pv;
  }
  __syncthreads();
  if (t < 16) nrm2g[(size_t)(s*BB + b)*NN + i0 + t] = n2[t];
  for (int idx = t; idx < 1024; idx += 256){
    int rr = idx >> 6, c = idx & 63;
    float rinv = 1.0f / fmaxf(sqrtf(n2[rr]), 1e-12f);
    fnT[((size_t)(s*BB + b)*CC + c)*NN + i0 + rr] = fr[rr][c]*rinv;
  }
  for (int idx = t; idx < 1024; idx += 256){
    int rr = idx >> 6, o = idx & 63;
    float acc = bias[o];
    #pragma unroll
    for (int c = 0; c < 64; c++) acc += fr[rr][c]*wl[o][c];
    p [((size_t)(s*BB + b)*NN + i0 + rr)*CC + o] = acc;
    pT[((size_t)(s*BB + b)*CC + o)*NN + i0 + rr] = acc;
  }
}

// ---------------- K1: per-(b,q) sum(D), sum(D^2) ----------------
#define R1 16
__global__ __launch_bounds__(256)
void k1(const float* __restrict__ x1, const float* __restrict__ x2, const float* __restrict__ x3,
        const float* __restrict__ f, const float* __restrict__ fnT,
        const float* __restrict__ nrm2g, double* __restrict__ sums){
  int bid = blockIdx.x;
  int tile = bid & 63;            // 64 tiles of 16 rows
  int q = (bid >> 6) % 9;
  int b = bid / 576;
  int r = q / 3, s = q - 3*r;
  bool euc = (r == s);
  int i0 = tile * R1;
  int t = threadIdx.x;
  __shared__ float yl[R1][64];
  __shared__ float yn2[R1];
  __shared__ float s1[4], s2[4];
  if (t < R1) yn2[t] = nrm2g[(size_t)(r*BB + b)*NN + i0 + t];
  __syncthreads();
  for (int idx = t; idx < R1*64; idx += 256){
    int rr = idx >> 6, c = idx & 63;
    float v = f[((size_t)(r*BB + b)*NN + i0 + rr)*CC + c];
    if (!euc) v *= 1.0f / fmaxf(sqrtf(yn2[rr]), 1e-12f);
    yl[rr][c] = v;
  }
  __syncthreads();
  const float* xs = (s==0)?x1:((s==1)?x2:x3);
  const float* colD = euc ? (xs + (size_t)(b*CC)*NN) : (fnT + (size_t)((s*BB + b)*CC)*NN);
  float acc[R1][4];
  #pragma unroll
  for (int rr=0; rr<R1; rr++){
    #pragma unroll
    for (int k=0;k<4;k++) acc[rr][k] = 0.f;
  }
  for (int c=0;c<CC;c++){
    float cv[4];
    #pragma unroll
    for (int k=0;k<4;k++) cv[k] = colD[(size_t)c*NN + t + k*256];
    #pragma unroll
    for (int rr=0; rr<R1; rr++){
      float yv = yl[rr][c];
      #pragma unroll
      for (int k=0;k<4;k++) acc[rr][k] += yv*cv[k];
    }
  }
  float cn2[4];
  if (euc){
    #pragma unroll
    for (int k=0;k<4;k++) cn2[k] = nrm2g[(size_t)(s*BB + b)*NN + t + k*256];
  }
  float sd = 0.f, sd2 = 0.f;
  #pragma unroll
  for (int rr=0; rr<R1; rr++){
    #pragma unroll
    for (int k=0;k<4;k++){
      float d;
      if (euc){
        float sq = yn2[rr] + cn2[k] - 2.0f*acc[rr][k];
        d = sqrtf(fmaxf(sq, 1e-12f));
      } else {
        d = 1.0f - acc[rr][k];
      }
      sd += d; sd2 += d*d;
    }
  }
  sd = wsum(sd); sd2 = wsum(sd2);
  int wid = t >> 6, lane = t & 63;
  if (lane == 0){ s1[wid] = sd; s2[wid] = sd2; }
  __syncthreads();
  if (t == 0){
    double S  = (double)s1[0] + (double)s1[1] + (double)s1[2] + (double)s1[3];
    double S2 = (double)s2[0] + (double)s2[1] + (double)s2[2] + (double)s2[3];
    atomicAdd(&sums[(b*9 + q)*2 + 0], S);
    atomicAdd(&sums[(b*9 + q)*2 + 1], S2);
  }
}

// ---------------- K2: mu + alpha*sigma ----------------
__global__ void k2(const double* __restrict__ sums, float* __restrict__ baseg){
  int t = threadIdx.x;
  if (t < 18){
    double S = sums[t*2], S2 = sums[t*2+1];
    const double Nsq = 1048576.0;
    double mu = S / Nsq;
    double var = (S2 - S*S/Nsq) / (Nsq - 1.0);
    double sg = var > 0.0 ? sqrt(var) : 0.0;
    baseg[t] = (float)(mu + 0.08*sg);
  }
}

// ---------------- K3: adjacency + attention + output ----------------
__global__ __launch_bounds__(256)
void k3(const float* __restrict__ x1, const float* __restrict__ x2, const float* __restrict__ x3,
        const float* __restrict__ f, const float* __restrict__ p,
        const float* __restrict__ fnT, const float* __restrict__ pT,
        const float* __restrict__ nrm2g, const float* __restrict__ baseg,
        float* __restrict__ out){
  __shared__ float Dl[4][NN];       // 16KB
  __shared__ float Pl[4][NN];       // 16KB  (becomes att rows)
  __shared__ ull   keys[NN];        // 8KB
  __shared__ float cum[NN];         // 4KB
  __shared__ float yl[4][CC];
  __shared__ float pyl[4][CC];
  __shared__ float yn2[4];
  __shared__ float r4a[4], r4b[4];
  __shared__ float opart[4][4][CC]; // 4KB

  int bid = blockIdx.x;
  int tile = bid & 255;             // 256 tiles of 4 rows
  int q = (bid >> 8) % 9;
  int b = bid / 2304;
  int r = q / 3, s = q - 3*r;
  bool euc = (r == s);
  int i0 = tile * 4;
  int t = threadIdx.x;
  int wid = t >> 6, lane = t & 63;

  if (t < 4) yn2[t] = nrm2g[(size_t)(r*BB + b)*NN + i0 + t];
  __syncthreads();
  for (int idx = t; idx < 4*CC; idx += 256){
    int rr = idx >> 6, c = idx & 63;
    float v = f[((size_t)(r*BB + b)*NN + i0 + rr)*CC + c];
    if (!euc) v *= 1.0f / fmaxf(sqrtf(yn2[rr]), 1e-12f);
    yl[rr][c] = v;
    pyl[rr][c] = p[((size_t)(r*BB + b)*NN + i0 + rr)*CC + c];
  }
  __syncthreads();

  const float* xs = (s==0)?x1:((s==1)?x2:x3);
  const float* colD = euc ? (xs + (size_t)(b*CC)*NN) : (fnT + (size_t)((s*BB + b)*CC)*NN);
  const float* colP = pT + (size_t)((s*BB + b)*CC)*NN;

  float ad[4][4], ap[4][4];
  #pragma unroll
  for (int rr=0; rr<4; rr++){
    #pragma unroll
    for (int k=0;k<4;k++){ ad[rr][k]=0.f; ap[rr][k]=0.f; }
  }
  for (int c=0;c<CC;c++){
    float cvd[4], cvp[4];
    #pragma unroll
    for (int k=0;k<4;k++){
      cvd[k] = colD[(size_t)c*NN + t + k*256];
      cvp[k] = colP[(size_t)c*NN + t + k*256];
    }
    #pragma unroll
    for (int rr=0;rr<4;rr++){
      float yv = yl[rr][c], pv = pyl[rr][c];
      #pragma unroll
      for (int k=0;k<4;k++){ ad[rr][k] += yv*cvd[k]; ap[rr][k] += pv*cvp[k]; }
    }
  }
  if (euc){
    float cn2[4];
    #pragma unroll
    for (int k=0;k<4;k++) cn2[k] = nrm2g[(size_t)(s*BB + b)*NN + t + k*256];
    #pragma unroll
    for (int rr=0;rr<4;rr++){
      #pragma unroll
      for (int k=0;k<4;k++){
        float sq = yn2[rr] + cn2[k] - 2.0f*ad[rr][k];
        Dl[rr][t + k*256] = sqrtf(fmaxf(sq, 1e-12f));
        Pl[rr][t + k*256] = ap[rr][k];
      }
    }
  } else {
    #pragma unroll
    for (int rr=0;rr<4;rr++){
      #pragma unroll
      for (int k=0;k<4;k++){
        Dl[rr][t + k*256] = 1.0f - ad[rr][k];
        Pl[rr][t + k*256] = ap[rr][k];
      }
    }
  }
  __syncthreads();

  float Tbase = baseg[b*9 + q];

  for (int rr = 0; rr < 4; rr++){
    float* Dr = Dl[rr];
    float* Pr = Pl[rr];
    // --- row min/max ---
    float lmin = 3.4e38f, lmax = -3.4e38f;
    #pragma unroll
    for (int k=0;k<4;k++){ float d = Dr[t+k*256]; lmin = fminf(lmin,d); lmax = fmaxf(lmax,d); }
    lmin = wminr(lmin); lmax = wmaxr(lmax);
    if (lane==0){ r4a[wid]=lmin; r4b[wid]=lmax; }
    __syncthreads();
    float Dmin = fminf(fminf(r4a[0],r4a[1]),fminf(r4a[2],r4a[3]));
    float Dmax = fmaxf(fmaxf(r4b[0],r4b[1]),fmaxf(r4b[2],r4b[3]));
    __syncthreads();
    // --- softmax denom ---
    float lz = 0.f;
    #pragma unroll
    for (int k=0;k<4;k++) lz += expf((Dmin - Dr[t+k*256])*0.1f);
    lz = wsum(lz);
    if (lane==0) r4a[wid]=lz;
    __syncthreads();
    float Z = r4a[0]+r4a[1]+r4a[2]+r4a[3];
    __syncthreads();
    float invZ = 1.0f/Z;
    // --- entropy / decay ---
    float le = 0.f;
    #pragma unroll
    for (int k=0;k<4;k++){
      float pp = expf((Dmin - Dr[t+k*256])*0.1f)*invZ;
      le += pp*logf(pp + 1e-8f);
    }
    le = wsum(le);
    if (lane==0) r4a[wid]=le;
    __syncthreads();
    float ent = -(r4a[0]+r4a[1]+r4a[2]+r4a[3]);
    __syncthreads();
    float decay = expf(-ent);
    // --- keys: stable ascending (D, idx) ---
    #pragma unroll
    for (int k=0;k<4;k++){
      int x = t + k*256;
      unsigned u = __float_as_uint(Dr[x]);
      u = (u & 0x80000000u) ? ~u : (u | 0x80000000u);
      keys[x] = ((ull)u << 32) | (unsigned)x;
    }
    __syncthreads();
    // --- bitonic sort 1024 ---
    for (int kk = 2; kk <= NN; kk <<= 1){
      for (int jj = kk >> 1; jj > 0; jj >>= 1){
        #pragma unroll
        for (int pi = 0; pi < 2; pi++){
          int pp = t + pi*256;
          int i = ((pp & ~(jj-1)) << 1) | (pp & (jj-1));
          int l = i | jj;
          ull a = keys[i], bk = keys[l];
          if ((a > bk) == ((i & kk) == 0)){ keys[i] = bk; keys[l] = a; }
        }
        __syncthreads();
      }
    }
    // --- sorted probs -> inclusive scan ---
    #pragma unroll
    for (int k=0;k<4;k++){
      int x = t + k*256;
      int jj = (int)(keys[x] & 0xFFFFFFFFu);
      cum[x] = expf((Dmin - Dr[jj])*0.1f)*invZ;
    }
    __syncthreads();
    for (int off = 1; off < NN; off <<= 1){
      float v[4];
      #pragma unroll
      for (int k=0;k<4;k++){
        int x = t + k*256;
        v[k] = cum[x] + ((x >= off) ? cum[x-off] : 0.f);
      }
      __syncthreads();
      #pragma unroll
      for (int k=0;k<4;k++) cum[t+k*256] = v[k];
      __syncthreads();
    }
    // --- select + mask + S (scatter into Pr) ---
    #pragma unroll
    for (int k=0;k<4;k++){
      int x = t + k*256;
      int jj = (int)(keys[x] & 0xFFFFFFFFu);
      float d = Dr[jj];
      float T = Tbase + 0.01f*(1.0f - d/Dmax)*decay;
      float sv = ((cum[x] <= 0.8f) && (d < T)) ? Pr[jj] : 0.f;
      Pr[jj] = sv;
    }
    __syncthreads();
    // --- softmax over S row ---
    float lm = -3.4e38f;
    #pragma unroll
    for (int k=0;k<4;k++) lm = fmaxf(lm, Pr[t+k*256]);
    lm = wmaxr(lm);
    if (lane==0) r4a[wid]=lm;
    __syncthreads();
    float M = fmaxf(fmaxf(r4a[0],r4a[1]),fmaxf(r4a[2],r4a[3]));
    __syncthreads();
    float ls = 0.f;
    #pragma unroll
    for (int k=0;k<4;k++) ls += expf(Pr[t+k*256]-M);
    ls = wsum(ls);
    if (lane==0) r4a[wid]=ls;
    __syncthreads();
    float Z2 = r4a[0]+r4a[1]+r4a[2]+r4a[3];
    __syncthreads();
    float iZ2 = 1.0f/Z2;
    #pragma unroll
    for (int k=0;k<4;k++){ int x=t+k*256; Pr[x] = expf(Pr[x]-M)*iZ2; }
    __syncthreads();
  }

  // --- o accumulation: o[rr][c] = sum_j att[rr][j]*f_s[j][c] ---
  const float* fs = f + (size_t)((s*BB + b)*NN)*CC;
  int g = t >> 6, c = t & 63;
  float ov0=0.f, ov1=0.f, ov2=0.f, ov3=0.f;
  int j0 = g*256;
  for (int j = j0; j < j0+256; j++){
    float fv = fs[(size_t)j*CC + c];
    ov0 += Pl[0][j]*fv;
    ov1 += Pl[1][j]*fv;
    ov2 += Pl[2][j]*fv;
    ov3 += Pl[3][j]*fv;
  }
  opart[g][0][c]=ov0; opart[g][1][c]=ov1; opart[g][2][c]=ov2; opart[g][3][c]=ov3;
  __syncthreads();
  {
    int rr = t >> 6, cc2 = t & 63;
    float v = opart[0][rr][cc2]+opart[1][rr][cc2]+opart[2][rr][cc2]+opart[3][rr][cc2];
    atomicAdd(&out[(size_t)(b*CC + cc2)*NN + i0 + rr], v);
  }
}

extern "C" void kernel_launch(void* const* d_in, const int* in_sizes, int n_in,
                              void* d_out, int out_size, void* d_ws, size_t ws_size,
                              hipStream_t stream){
  const float* x1 = (const float*)d_in[0];
  const float* x2 = (const float*)d_in[1];
  const float* x3 = (const float*)d_in[2];
  const float* w1 = (const float*)d_in[3];
  const float* b1 = (const float*)d_in[4];
  const float* w2 = (const float*)d_in[5];
  const float* b2 = (const float*)d_in[6];
  const float* w3 = (const float*)d_in[7];
  const float* b3 = (const float*)d_in[8];

  char* ws = (char*)d_ws;
  const size_t SZ = (size_t)3*BB*NN*CC*sizeof(float);   // 1.5MB each
  float*  f    = (float*)(ws);
  float*  p    = (float*)(ws + SZ);
  float*  fnT  = (float*)(ws + 2*SZ);
  float*  pT   = (float*)(ws + 3*SZ);
  float*  nrm2 = (float*)(ws + 4*SZ);
  double* sums = (double*)(ws + 4*SZ + 32768);
  float*  baseg= (float*)(ws + 4*SZ + 32768 + 512);

  float* out = (float*)d_out;

  kz <<<512, 256, 0, stream>>>(out, sums);
  k0a<<<96,  256, 0, stream>>>(x1, x2, x3, f);
  k0b<<<384, 256, 0, stream>>>(f, w1, b1, w2, b2, w3, b3, p, pT, fnT, nrm2);
  k1 <<<1152,256, 0, stream>>>(x1, x2, x3, f, fnT, nrm2, sums);
  k2 <<<1,   64,  0, stream>>>(sums, baseg);
  k3 <<<4608,256, 0, stream>>>(x1, x2, x3, f, p, fnT, pT, nrm2, baseg, out);
}

// Round 2
// 426.936 us; speedup vs baseline: 1.8221x; 1.8221x over previous
//
#include <hip/hip_runtime.h>

#define NN 1024
#define CC 64
#define BB 2

typedef unsigned long long ull;

__device__ __forceinline__ float wsum(float v){
  #pragma unroll
  for (int o=32;o;o>>=1) v += __shfl_xor(v,o);
  return v;
}
__device__ __forceinline__ float wmaxr(float v){
  #pragma unroll
  for (int o=32;o;o>>=1) v = fmaxf(v, __shfl_xor(v,o));
  return v;
}
__device__ __forceinline__ float wminr(float v){
  #pragma unroll
  for (int o=32;o;o>>=1) v = fminf(v, __shfl_xor(v,o));
  return v;
}

// ---------------- zero init ----------------
__global__ void kz(float* __restrict__ out, double* __restrict__ sums){
  int i = blockIdx.x*256 + threadIdx.x;
  if (i < BB*CC*NN) out[i] = 0.0f;
  if (i < 36) sums[i] = 0.0;
}

// ---------------- K0a: transpose x[b][c][n] -> f[s][b][n][c] ----------------
__global__ __launch_bounds__(256)
void k0a(const float* __restrict__ x1, const float* __restrict__ x2, const float* __restrict__ x3,
         float* __restrict__ f){
  int bid = blockIdx.x;
  int tile = bid & 15;        // 16 tiles of 64 i
  int b = (bid >> 4) & 1;
  int s = bid >> 5;
  const float* x = (s==0)?x1:((s==1)?x2:x3);
  __shared__ float lds[64][65];
  int i0 = tile*64;
  for (int idx = threadIdx.x; idx < 4096; idx += 256){
    int c = idx >> 6, ii = idx & 63;
    lds[c][ii] = x[(size_t)(b*CC + c)*NN + i0 + ii];
  }
  __syncthreads();
  for (int idx = threadIdx.x; idx < 4096; idx += 256){
    int ii = idx >> 6, c = idx & 63;
    f[((size_t)(s*BB + b)*NN + i0 + ii)*CC + c] = lds[c][ii];
  }
}

// ---------------- K0b: norms, fnT, p, pT ----------------
__global__ __launch_bounds__(256)
void k0b(const float* __restrict__ f,
         const float* __restrict__ w1, const float* __restrict__ b1,
         const float* __restrict__ w2, const float* __restrict__ b2,
         const float* __restrict__ w3, const float* __restrict__ b3,
         float* __restrict__ p, float* __restrict__ pT,
         float* __restrict__ fnT, float* __restrict__ nrm2g){
  int bid = blockIdx.x;
  int chunk = bid & 63;       // 64 chunks of 16 rows
  int b = (bid >> 6) & 1;
  int s = bid >> 7;
  const float* w = (s==0)?w1:((s==1)?w2:w3);
  const float* bias = (s==0)?b1:((s==1)?b2:b3);
  __shared__ float wl[64][65];
  __shared__ float fr[16][65];
  __shared__ float n2[16];
  int i0 = chunk*16;
  int t = threadIdx.x;
  for (int idx = t; idx < 4096; idx += 256){
    int o = idx >> 6, c = idx & 63;
    wl[o][c] = w[idx];
  }
  for (int idx = t; idx < 1024; idx += 256){
    int rr = idx >> 6, c = idx & 63;
    fr[rr][c] = f[((size_t)(s*BB + b)*NN + i0 + rr)*CC + c];
  }
  __syncthreads();
  {
    int r = t >> 4, l = t & 15;
    float pv = 0.f;
    for (int c = l; c < 64; c += 16) pv += fr[r][c]*fr[r][c];
    #pragma unroll
    for (int o=8;o;o>>=1) pv += __shfl_down(pv, o, 16);
    if (l == 0) n2[r] = pv;
  }
  __syncthreads();
  if (t < 16) nrm2g[(size_t)(s*BB + b)*NN + i0 + t] = n2[t];
  for (int idx = t; idx < 1024; idx += 256){
    int rr = idx >> 6, c = idx & 63;
    float rinv = 1.0f / fmaxf(sqrtf(n2[rr]), 1e-12f);
    fnT[((size_t)(s*BB + b)*CC + c)*NN + i0 + rr] = fr[rr][c]*rinv;
  }
  for (int idx = t; idx < 1024; idx += 256){
    int rr = idx >> 6, o = idx & 63;
    float acc = bias[o];
    #pragma unroll
    for (int c = 0; c < 64; c++) acc += fr[rr][c]*wl[o][c];
    p [((size_t)(s*BB + b)*NN + i0 + rr)*CC + o] = acc;
    pT[((size_t)(s*BB + b)*CC + o)*NN + i0 + rr] = acc;
  }
}

// ---------------- K1: per-(b,q) sum(D), sum(D^2) ----------------
#define R1 16
__global__ __launch_bounds__(256)
void k1(const float* __restrict__ x1, const float* __restrict__ x2, const float* __restrict__ x3,
        const float* __restrict__ f, const float* __restrict__ fnT,
        const float* __restrict__ nrm2g, double* __restrict__ sums){
  int bid = blockIdx.x;
  int tile = bid & 63;            // 64 tiles of 16 rows
  int q = (bid >> 6) % 9;
  int b = bid / 576;
  int r = q / 3, s = q - 3*r;
  bool euc = (r == s);
  int i0 = tile * R1;
  int t = threadIdx.x;
  __shared__ float yl[R1][64];
  __shared__ float yn2[R1];
  __shared__ float s1[4], s2[4];
  if (t < R1) yn2[t] = nrm2g[(size_t)(r*BB + b)*NN + i0 + t];
  __syncthreads();
  for (int idx = t; idx < R1*64; idx += 256){
    int rr = idx >> 6, c = idx & 63;
    float v = f[((size_t)(r*BB + b)*NN + i0 + rr)*CC + c];
    if (!euc) v *= 1.0f / fmaxf(sqrtf(yn2[rr]), 1e-12f);
    yl[rr][c] = v;
  }
  __syncthreads();
  const float* xs = (s==0)?x1:((s==1)?x2:x3);
  const float* colD = euc ? (xs + (size_t)(b*CC)*NN) : (fnT + (size_t)((s*BB + b)*CC)*NN);
  float acc[R1][4];
  #pragma unroll
  for (int rr=0; rr<R1; rr++){
    #pragma unroll
    for (int k=0;k<4;k++) acc[rr][k] = 0.f;
  }
  for (int c=0;c<CC;c++){
    float cv[4];
    #pragma unroll
    for (int k=0;k<4;k++) cv[k] = colD[(size_t)c*NN + t + k*256];
    #pragma unroll
    for (int rr=0; rr<R1; rr++){
      float yv = yl[rr][c];
      #pragma unroll
      for (int k=0;k<4;k++) acc[rr][k] += yv*cv[k];
    }
  }
  float cn2[4];
  if (euc){
    #pragma unroll
    for (int k=0;k<4;k++) cn2[k] = nrm2g[(size_t)(s*BB + b)*NN + t + k*256];
  }
  float sd = 0.f, sd2 = 0.f;
  #pragma unroll
  for (int rr=0; rr<R1; rr++){
    #pragma unroll
    for (int k=0;k<4;k++){
      float d;
      if (euc){
        float sq = yn2[rr] + cn2[k] - 2.0f*acc[rr][k];
        d = sqrtf(fmaxf(sq, 1e-12f));
      } else {
        d = 1.0f - acc[rr][k];
      }
      sd += d; sd2 += d*d;
    }
  }
  sd = wsum(sd); sd2 = wsum(sd2);
  int wid = t >> 6, lane = t & 63;
  if (lane == 0){ s1[wid] = sd; s2[wid] = sd2; }
  __syncthreads();
  if (t == 0){
    double S  = (double)s1[0] + (double)s1[1] + (double)s1[2] + (double)s1[3];
    double S2 = (double)s2[0] + (double)s2[1] + (double)s2[2] + (double)s2[3];
    atomicAdd(&sums[(b*9 + q)*2 + 0], S);
    atomicAdd(&sums[(b*9 + q)*2 + 1], S2);
  }
}

// ---------------- K2: mu + alpha*sigma ----------------
__global__ void k2(const double* __restrict__ sums, float* __restrict__ baseg){
  int t = threadIdx.x;
  if (t < 18){
    double S = sums[t*2], S2 = sums[t*2+1];
    const double Nsq = 1048576.0;
    double mu = S / Nsq;
    double var = (S2 - S*S/Nsq) / (Nsq - 1.0);
    double sg = var > 0.0 ? sqrt(var) : 0.0;
    baseg[t] = (float)(mu + 0.08*sg);
  }
}

// ---------------- K3: adjacency + attention + output ----------------
// Rows go wave-parallel: wave w owns row w (16 elems/lane in registers).
// Top-p selection via 2-level 256-way weighted bucket descent (no sort).
__global__ __launch_bounds__(256, 3)
void k3(const float* __restrict__ x1, const float* __restrict__ x2, const float* __restrict__ x3,
        const float* __restrict__ f, const float* __restrict__ p,
        const float* __restrict__ fnT, const float* __restrict__ pT,
        const float* __restrict__ nrm2g, const float* __restrict__ baseg,
        float* __restrict__ out){
  __shared__ float Dl[4][NN];       // 16KB distances
  __shared__ float Sl[4][NN];       // 16KB logits -> att probs
  __shared__ float hist[4][256];    // 4KB  per-row weighted histogram
  __shared__ int   cand[4][64];     // 1KB
  __shared__ int   flg[4][64];      // 1KB
  __shared__ int   cnt4[4];
  __shared__ int   selI4[4];
  __shared__ float selC4[4];
  __shared__ float yl[4][CC];
  __shared__ float pyl[4][CC];
  __shared__ float yn2[4];
  __shared__ float opart[4][4][CC]; // 4KB

  int bid = blockIdx.x;
  int tile = bid & 255;             // 256 tiles of 4 rows
  int q = (bid >> 8) % 9;
  int b = bid / 2304;
  int r = q / 3, s = q - 3*r;
  bool euc = (r == s);
  int i0 = tile * 4;
  int t = threadIdx.x;
  int w = t >> 6, lane = t & 63;

  if (t < 4) yn2[t] = nrm2g[(size_t)(r*BB + b)*NN + i0 + t];
  __syncthreads();
  for (int idx = t; idx < 4*CC; idx += 256){
    int rr = idx >> 6, c = idx & 63;
    float v = f[((size_t)(r*BB + b)*NN + i0 + rr)*CC + c];
    if (!euc) v *= 1.0f / fmaxf(sqrtf(yn2[rr]), 1e-12f);
    yl[rr][c] = v;
    pyl[rr][c] = p[((size_t)(r*BB + b)*NN + i0 + rr)*CC + c];
  }
  __syncthreads();

  const float* xs = (s==0)?x1:((s==1)?x2:x3);
  const float* colD = euc ? (xs + (size_t)(b*CC)*NN) : (fnT + (size_t)((s*BB + b)*CC)*NN);
  const float* colP = pT + (size_t)((s*BB + b)*CC)*NN;

  {
    float ad[4][4], ap[4][4];
    #pragma unroll
    for (int rr=0; rr<4; rr++){
      #pragma unroll
      for (int k=0;k<4;k++){ ad[rr][k]=0.f; ap[rr][k]=0.f; }
    }
    for (int c=0;c<CC;c++){
      float cvd[4], cvp[4];
      #pragma unroll
      for (int k=0;k<4;k++){
        cvd[k] = colD[(size_t)c*NN + t + k*256];
        cvp[k] = colP[(size_t)c*NN + t + k*256];
      }
      #pragma unroll
      for (int rr=0;rr<4;rr++){
        float yv = yl[rr][c], pv = pyl[rr][c];
        #pragma unroll
        for (int k=0;k<4;k++){ ad[rr][k] += yv*cvd[k]; ap[rr][k] += pv*cvp[k]; }
      }
    }
    if (euc){
      float cn2[4];
      #pragma unroll
      for (int k=0;k<4;k++) cn2[k] = nrm2g[(size_t)(s*BB + b)*NN + t + k*256];
      #pragma unroll
      for (int rr=0;rr<4;rr++){
        #pragma unroll
        for (int k=0;k<4;k++){
          float sq = yn2[rr] + cn2[k] - 2.0f*ad[rr][k];
          Dl[rr][t + k*256] = sqrtf(fmaxf(sq, 1e-12f));
          Sl[rr][t + k*256] = ap[rr][k];
        }
      }
    } else {
      #pragma unroll
      for (int rr=0;rr<4;rr++){
        #pragma unroll
        for (int k=0;k<4;k++){
          Dl[rr][t + k*256] = 1.0f - ad[rr][k];
          Sl[rr][t + k*256] = ap[rr][k];
        }
      }
    }
  }
  __syncthreads();

  float Tbase = baseg[b*9 + q];

  // ======== wave-parallel row phase: wave w owns row w ========
  float dreg[16], preg[16];
  #pragma unroll
  for (int k=0;k<16;k++) dreg[k] = Dl[w][lane + 64*k];

  // row min/max
  float lmin = 3.4e38f, lmax = -3.4e38f;
  #pragma unroll
  for (int k=0;k<16;k++){ lmin = fminf(lmin,dreg[k]); lmax = fmaxf(lmax,dreg[k]); }
  float Dmin = wminr(lmin);
  float Dmax = wmaxr(lmax);

  // softmax denom over -D/tau (shifted by max = -Dmin/tau)
  float lz = 0.f;
  #pragma unroll
  for (int k=0;k<16;k++) lz += expf((Dmin - dreg[k])*0.1f);
  float Z = wsum(lz);
  float invZ = 1.0f/Z;
  #pragma unroll
  for (int k=0;k<16;k++) preg[k] = expf((Dmin - dreg[k])*0.1f)*invZ;

  // entropy / decay
  float le = 0.f;
  #pragma unroll
  for (int k=0;k<16;k++) le += preg[k]*logf(preg[k] + 1e-8f);
  float ent = -wsum(le);
  float decay = expf(-ent);

  float range = Dmax - Dmin;
  float scale1 = 256.0f / fmaxf(range, 1e-30f);

  // ---- level 1: 256-bucket weighted histogram over [Dmin, Dmax] ----
  #pragma unroll
  for (int i=0;i<4;i++) hist[w][lane*4+i] = 0.f;
  __syncthreads();
  #pragma unroll
  for (int k=0;k<16;k++){
    int b1 = (int)((dreg[k]-Dmin)*scale1); b1 = (b1>255)?255:b1;
    atomicAdd(&hist[w][b1], preg[k]);
  }
  __syncthreads();
  {
    float h0=hist[w][lane*4+0], h1=hist[w][lane*4+1], h2=hist[w][lane*4+2], h3=hist[w][lane*4+3];
    float tot = h0+h1+h2+h3;
    float incl = tot;
    #pragma unroll
    for (int o=1;o<64;o<<=1){ float v = __shfl_up(incl,o); if (lane>=o) incl += v; }
    float excl = incl - tot;
    float c0=excl, c1=excl+h0, c2=c1+h1, c3=c2+h2;
    if (c0<=0.8f && 0.8f<c0+h0){ selI4[w]=lane*4+0; selC4[w]=c0; }
    if (c1<=0.8f && 0.8f<c1+h1){ selI4[w]=lane*4+1; selC4[w]=c1; }
    if (c2<=0.8f && 0.8f<c2+h2){ selI4[w]=lane*4+2; selC4[w]=c2; }
    if (c3<=0.8f && 0.8f<c3+h3){ selI4[w]=lane*4+3; selC4[w]=c3; }
  }
  __syncthreads();
  int B1 = selI4[w]; float cb1 = selC4[w];
  float lo2 = Dmin + (float)B1/scale1;
  float scale2 = scale1*256.0f;

  // ---- level 2: refine within bucket B1 ----
  #pragma unroll
  for (int i=0;i<4;i++) hist[w][lane*4+i] = 0.f;
  if (lane==0) cnt4[w] = 0;
  __syncthreads();
  #pragma unroll
  for (int k=0;k<16;k++){
    int b1 = (int)((dreg[k]-Dmin)*scale1); b1 = (b1>255)?255:b1;
    if (b1 == B1){
      int b2 = (int)((dreg[k]-lo2)*scale2); b2 = (b2<0)?0:((b2>255)?255:b2);
      atomicAdd(&hist[w][b2], preg[k]);
    }
  }
  __syncthreads();
  {
    float h0=hist[w][lane*4+0], h1=hist[w][lane*4+1], h2=hist[w][lane*4+2], h3=hist[w][lane*4+3];
    float tot = h0+h1+h2+h3;
    float incl = tot;
    #pragma unroll
    for (int o=1;o<64;o<<=1){ float v = __shfl_up(incl,o); if (lane>=o) incl += v; }
    float excl = incl - tot;
    float c0=cb1+excl, c1=c0+h0, c2=c1+h1, c3=c2+h2;
    if (c0<=0.8f && 0.8f<c0+h0){ selI4[w]=lane*4+0; selC4[w]=c0; }
    if (c1<=0.8f && 0.8f<c1+h1){ selI4[w]=lane*4+1; selC4[w]=c1; }
    if (c2<=0.8f && 0.8f<c2+h2){ selI4[w]=lane*4+2; selC4[w]=c2; }
    if (c3<=0.8f && 0.8f<c3+h3){ selI4[w]=lane*4+3; selC4[w]=c3; }
  }
  __syncthreads();
  int B2 = selI4[w]; float cb2 = selC4[w];

  // ---- collect candidates in final sub-bucket ----
  #pragma unroll
  for (int k=0;k<16;k++){
    int b1 = (int)((dreg[k]-Dmin)*scale1); b1 = (b1>255)?255:b1;
    if (b1 == B1){
      int b2 = (int)((dreg[k]-lo2)*scale2); b2 = (b2<0)?0:((b2>255)?255:b2);
      if (b2 == B2){
        int c = atomicAdd(&cnt4[w], 1);
        if (c < 64) cand[w][c] = lane + 64*k;
      }
    }
  }
  __syncthreads();
  // ---- exact tie-resolving walk over candidates (lane 0 of wave) ----
  if (lane == 0){
    int n = cnt4[w]; n = (n>64)?64:n;
    for (int a=0;a<n;a++){
      int ja = cand[w][a]; float da = Dl[w][ja];
      float acc = cb2;
      for (int bb=0;bb<n;bb++){
        int jb = cand[w][bb]; float db = Dl[w][jb];
        if (db < da || (db == da && jb <= ja))
          acc += expf((Dmin - db)*0.1f)*invZ;
      }
      flg[w][a] = (acc <= 0.8f) ? 1 : 0;
    }
  }
  __syncthreads();
  int ncand = cnt4[w]; ncand = (ncand>64)?64:ncand;

  // ---- final mask + S + softmax (in registers) ----
  float sreg[16];
  #pragma unroll
  for (int k=0;k<16;k++){
    int j = lane + 64*k;
    float d = dreg[k];
    int b1 = (int)((d-Dmin)*scale1); b1 = (b1>255)?255:b1;
    int sel;
    if (b1 < B1) sel = 1;
    else if (b1 > B1) sel = 0;
    else {
      int b2 = (int)((d-lo2)*scale2); b2 = (b2<0)?0:((b2>255)?255:b2);
      if (b2 < B2) sel = 1;
      else if (b2 > B2) sel = 0;
      else {
        sel = 0;
        for (int c2=0;c2<ncand;c2++) if (cand[w][c2]==j) sel = flg[w][c2];
      }
    }
    float T = Tbase + 0.01f*(1.0f - d/Dmax)*decay;
    sreg[k] = (sel && (d < T)) ? Sl[w][j] : 0.f;
  }
  float lm = -3.4e38f;
  #pragma unroll
  for (int k=0;k<16;k++) lm = fmaxf(lm, sreg[k]);
  float M = wmaxr(lm);
  float ls = 0.f;
  #pragma unroll
  for (int k=0;k<16;k++) ls += expf(sreg[k]-M);
  float Z2 = wsum(ls);
  float iZ2 = 1.0f/Z2;
  #pragma unroll
  for (int k=0;k<16;k++) Sl[w][lane + 64*k] = expf(sreg[k]-M)*iZ2;
  __syncthreads();

  // ---- o accumulation: o[rr][c] = sum_j att[rr][j]*f_s[j][c] ----
  const float* fs = f + (size_t)((s*BB + b)*NN)*CC;
  int g = t >> 6, c = t & 63;
  float ov0=0.f, ov1=0.f, ov2=0.f, ov3=0.f;
  int j0 = g*256;
  for (int j = j0; j < j0+256; j++){
    float fv = fs[(size_t)j*CC + c];
    ov0 += Sl[0][j]*fv;
    ov1 += Sl[1][j]*fv;
    ov2 += Sl[2][j]*fv;
    ov3 += Sl[3][j]*fv;
  }
  opart[g][0][c]=ov0; opart[g][1][c]=ov1; opart[g][2][c]=ov2; opart[g][3][c]=ov3;
  __syncthreads();
  {
    int rr = t >> 6, cc2 = t & 63;
    float v = opart[0][rr][cc2]+opart[1][rr][cc2]+opart[2][rr][cc2]+opart[3][rr][cc2];
    atomicAdd(&out[(size_t)(b*CC + cc2)*NN + i0 + rr], v);
  }
}

extern "C" void kernel_launch(void* const* d_in, const int* in_sizes, int n_in,
                              void* d_out, int out_size, void* d_ws, size_t ws_size,
                              hipStream_t stream){
  const float* x1 = (const float*)d_in[0];
  const float* x2 = (const float*)d_in[1];
  const float* x3 = (const float*)d_in[2];
  const float* w1 = (const float*)d_in[3];
  const float* b1 = (const float*)d_in[4];
  const float* w2 = (const float*)d_in[5];
  const float* b2 = (const float*)d_in[6];
  const float* w3 = (const float*)d_in[7];
  const float* b3 = (const float*)d_in[8];

  char* ws = (char*)d_ws;
  const size_t SZ = (size_t)3*BB*NN*CC*sizeof(float);   // 1.5MB each
  float*  f    = (float*)(ws);
  float*  p    = (float*)(ws + SZ);
  float*  fnT  = (float*)(ws + 2*SZ);
  float*  pT   = (float*)(ws + 3*SZ);
  float*  nrm2 = (float*)(ws + 4*SZ);
  double* sums = (double*)(ws + 4*SZ + 32768);
  float*  baseg= (float*)(ws + 4*SZ + 32768 + 512);

  float* out = (float*)d_out;

  kz <<<512, 256, 0, stream>>>(out, sums);
  k0a<<<96,  256, 0, stream>>>(x1, x2, x3, f);
  k0b<<<384, 256, 0, stream>>>(f, w1, b1, w2, b2, w3, b3, p, pT, fnT, nrm2);
  k1 <<<1152,256, 0, stream>>>(x1, x2, x3, f, fnT, nrm2, sums);
  k2 <<<1,   64,  0, stream>>>(sums, baseg);
  k3 <<<4608,256, 0, stream>>>(x1, x2, x3, f, p, fnT, pT, nrm2, baseg, out);
}

// Round 3
// 372.779 us; speedup vs baseline: 2.0869x; 1.1453x over previous
//
#include <hip/hip_runtime.h>

#define NN 1024
#define CC 64
#define BB 2

typedef unsigned long long ull;

__device__ __forceinline__ float wsum(float v){
  #pragma unroll
  for (int o=32;o;o>>=1) v += __shfl_xor(v,o);
  return v;
}
__device__ __forceinline__ float wmaxr(float v){
  #pragma unroll
  for (int o=32;o;o>>=1) v = fmaxf(v, __shfl_xor(v,o));
  return v;
}
__device__ __forceinline__ float wminr(float v){
  #pragma unroll
  for (int o=32;o;o>>=1) v = fminf(v, __shfl_xor(v,o));
  return v;
}
__device__ __forceinline__ float4 ld4(const float* p){ return *reinterpret_cast<const float4*>(p); }

// ---------------- zero init ----------------
__global__ void kz(float* __restrict__ out, double* __restrict__ sums){
  int i = blockIdx.x*256 + threadIdx.x;
  if (i < BB*CC*NN) out[i] = 0.0f;
  if (i < 36) sums[i] = 0.0;
}

// ---------------- K0a: transpose x[b][c][n] -> f[s][b][n][c] ----------------
__global__ __launch_bounds__(256)
void k0a(const float* __restrict__ x1, const float* __restrict__ x2, const float* __restrict__ x3,
         float* __restrict__ f){
  int bid = blockIdx.x;
  int tile = bid & 15;
  int b = (bid >> 4) & 1;
  int s = bid >> 5;
  const float* x = (s==0)?x1:((s==1)?x2:x3);
  __shared__ float lds[64][65];
  int i0 = tile*64;
  for (int idx = threadIdx.x; idx < 4096; idx += 256){
    int c = idx >> 6, ii = idx & 63;
    lds[c][ii] = x[(size_t)(b*CC + c)*NN + i0 + ii];
  }
  __syncthreads();
  for (int idx = threadIdx.x; idx < 4096; idx += 256){
    int ii = idx >> 6, c = idx & 63;
    f[((size_t)(s*BB + b)*NN + i0 + ii)*CC + c] = lds[c][ii];
  }
}

// ---------------- K0b: norms, fnT, p, pT ----------------
__global__ __launch_bounds__(256)
void k0b(const float* __restrict__ f,
         const float* __restrict__ w1, const float* __restrict__ b1,
         const float* __restrict__ w2, const float* __restrict__ b2,
         const float* __restrict__ w3, const float* __restrict__ b3,
         float* __restrict__ p, float* __restrict__ pT,
         float* __restrict__ fnT, float* __restrict__ nrm2g){
  int bid = blockIdx.x;
  int chunk = bid & 63;
  int b = (bid >> 6) & 1;
  int s = bid >> 7;
  const float* w = (s==0)?w1:((s==1)?w2:w3);
  const float* bias = (s==0)?b1:((s==1)?b2:b3);
  __shared__ float wl[64][65];
  __shared__ float fr[16][65];
  __shared__ float n2[16];
  int i0 = chunk*16;
  int t = threadIdx.x;
  for (int idx = t; idx < 4096; idx += 256){
    int o = idx >> 6, c = idx & 63;
    wl[o][c] = w[idx];
  }
  for (int idx = t; idx < 1024; idx += 256){
    int rr = idx >> 6, c = idx & 63;
    fr[rr][c] = f[((size_t)(s*BB + b)*NN + i0 + rr)*CC + c];
  }
  __syncthreads();
  {
    int r = t >> 4, l = t & 15;
    float pv = 0.f;
    for (int c = l; c < 64; c += 16) pv += fr[r][c]*fr[r][c];
    #pragma unroll
    for (int o=8;o;o>>=1) pv += __shfl_down(pv, o, 16);
    if (l == 0) n2[r] = pv;
  }
  __syncthreads();
  if (t < 16) nrm2g[(size_t)(s*BB + b)*NN + i0 + t] = n2[t];
  for (int idx = t; idx < 1024; idx += 256){
    int rr = idx >> 6, c = idx & 63;
    float rinv = 1.0f / fmaxf(sqrtf(n2[rr]), 1e-12f);
    fnT[((size_t)(s*BB + b)*CC + c)*NN + i0 + rr] = fr[rr][c]*rinv;
  }
  for (int idx = t; idx < 1024; idx += 256){
    int rr = idx >> 6, o = idx & 63;
    float acc = bias[o];
    #pragma unroll
    for (int c = 0; c < 64; c++) acc += fr[rr][c]*wl[o][c];
    p [((size_t)(s*BB + b)*NN + i0 + rr)*CC + o] = acc;
    pT[((size_t)(s*BB + b)*CC + o)*NN + i0 + rr] = acc;
  }
}

// ---------------- K2: mu + alpha*sigma ----------------
__global__ void k2(const double* __restrict__ sums, float* __restrict__ baseg){
  int t = threadIdx.x;
  if (t < 18){
    double S = sums[t*2], S2 = sums[t*2+1];
    const double Nsq = 1048576.0;
    double mu = S / Nsq;
    double var = (S2 - S*S/Nsq) / (Nsq - 1.0);
    double sg = var > 0.0 ? sqrt(var) : 0.0;
    baseg[t] = (float)(mu + 0.08*sg);
  }
}

// ================= PATH A (big workspace) =================
// K1a: 8-row-tile GEMM: computes D and S(logits), stores both, accumulates sums.
__global__ __launch_bounds__(256)
void k1a(const float* __restrict__ x1, const float* __restrict__ x2, const float* __restrict__ x3,
         const float* __restrict__ f, const float* __restrict__ p,
         const float* __restrict__ fnT, const float* __restrict__ pT,
         const float* __restrict__ nrm2g, double* __restrict__ sums,
         float* __restrict__ Dg, float* __restrict__ Sg){
  int bid = blockIdx.x;
  int tile = bid & 127;
  int q = (bid >> 7) % 9;
  int b = bid / 1152;
  int r = q / 3, s = q - 3*r;
  bool euc = (r == s);
  int m = b*9 + q;
  int i0 = tile * 8;
  int t = threadIdx.x;
  __shared__ __align__(16) float yl[8][64];
  __shared__ __align__(16) float pyl[8][64];
  __shared__ float yn2[8];
  __shared__ float s1[4], s2[4];
  if (t < 8) yn2[t] = nrm2g[(size_t)(r*BB + b)*NN + i0 + t];
  __syncthreads();
  for (int idx = t; idx < 512; idx += 256){
    int rr = idx >> 6, c = idx & 63;
    float v = f[((size_t)(r*BB + b)*NN + i0 + rr)*CC + c];
    if (!euc) v *= 1.0f / fmaxf(sqrtf(yn2[rr]), 1e-12f);
    yl[rr][c] = v;
    pyl[rr][c] = p[((size_t)(r*BB + b)*NN + i0 + rr)*CC + c];
  }
  __syncthreads();
  const float* xs = (s==0)?x1:((s==1)?x2:x3);
  const float* colD = euc ? (xs + (size_t)(b*CC)*NN) : (fnT + (size_t)((s*BB + b)*CC)*NN);
  const float* colP = pT + (size_t)((s*BB + b)*CC)*NN;
  int j4 = 4*t;
  float ad[8][4], ap[8][4];
  #pragma unroll
  for (int rr=0;rr<8;rr++){
    #pragma unroll
    for (int i=0;i<4;i++){ ad[rr][i]=0.f; ap[rr][i]=0.f; }
  }
  #pragma unroll 4
  for (int cc=0; cc<16; cc++){
    float4 cd0 = ld4(colD + (size_t)(cc*4+0)*NN + j4);
    float4 cd1 = ld4(colD + (size_t)(cc*4+1)*NN + j4);
    float4 cd2 = ld4(colD + (size_t)(cc*4+2)*NN + j4);
    float4 cd3 = ld4(colD + (size_t)(cc*4+3)*NN + j4);
    float4 cp0 = ld4(colP + (size_t)(cc*4+0)*NN + j4);
    float4 cp1 = ld4(colP + (size_t)(cc*4+1)*NN + j4);
    float4 cp2 = ld4(colP + (size_t)(cc*4+2)*NN + j4);
    float4 cp3 = ld4(colP + (size_t)(cc*4+3)*NN + j4);
    #pragma unroll
    for (int rr=0;rr<8;rr++){
      float4 y4 = *reinterpret_cast<const float4*>(&yl[rr][cc*4]);
      ad[rr][0] += y4.x*cd0.x + y4.y*cd1.x + y4.z*cd2.x + y4.w*cd3.x;
      ad[rr][1] += y4.x*cd0.y + y4.y*cd1.y + y4.z*cd2.y + y4.w*cd3.y;
      ad[rr][2] += y4.x*cd0.z + y4.y*cd1.z + y4.z*cd2.z + y4.w*cd3.z;
      ad[rr][3] += y4.x*cd0.w + y4.y*cd1.w + y4.z*cd2.w + y4.w*cd3.w;
      float4 p4 = *reinterpret_cast<const float4*>(&pyl[rr][cc*4]);
      ap[rr][0] += p4.x*cp0.x + p4.y*cp1.x + p4.z*cp2.x + p4.w*cp3.x;
      ap[rr][1] += p4.x*cp0.y + p4.y*cp1.y + p4.z*cp2.y + p4.w*cp3.y;
      ap[rr][2] += p4.x*cp0.z + p4.y*cp1.z + p4.z*cp2.z + p4.w*cp3.z;
      ap[rr][3] += p4.x*cp0.w + p4.y*cp1.w + p4.z*cp2.w + p4.w*cp3.w;
    }
  }
  float4 cn2v = make_float4(0.f,0.f,0.f,0.f);
  if (euc) cn2v = ld4(nrm2g + (size_t)(s*BB + b)*NN + j4);
  float sd = 0.f, sd2 = 0.f;
  float* Dm = Dg + (size_t)m*NN*NN;
  float* Sm = Sg + (size_t)m*NN*NN;
  #pragma unroll
  for (int rr=0;rr<8;rr++){
    float dv[4];
    if (euc){
      dv[0] = sqrtf(fmaxf(yn2[rr] + cn2v.x - 2.0f*ad[rr][0], 1e-12f));
      dv[1] = sqrtf(fmaxf(yn2[rr] + cn2v.y - 2.0f*ad[rr][1], 1e-12f));
      dv[2] = sqrtf(fmaxf(yn2[rr] + cn2v.z - 2.0f*ad[rr][2], 1e-12f));
      dv[3] = sqrtf(fmaxf(yn2[rr] + cn2v.w - 2.0f*ad[rr][3], 1e-12f));
    } else {
      dv[0] = 1.0f - ad[rr][0]; dv[1] = 1.0f - ad[rr][1];
      dv[2] = 1.0f - ad[rr][2]; dv[3] = 1.0f - ad[rr][3];
    }
    sd  += dv[0]+dv[1]+dv[2]+dv[3];
    sd2 += dv[0]*dv[0]+dv[1]*dv[1]+dv[2]*dv[2]+dv[3]*dv[3];
    float4 o4; o4.x=dv[0]; o4.y=dv[1]; o4.z=dv[2]; o4.w=dv[3];
    *reinterpret_cast<float4*>(Dm + (size_t)(i0+rr)*NN + j4) = o4;
    float4 s4; s4.x=ap[rr][0]; s4.y=ap[rr][1]; s4.z=ap[rr][2]; s4.w=ap[rr][3];
    *reinterpret_cast<float4*>(Sm + (size_t)(i0+rr)*NN + j4) = s4;
  }
  sd = wsum(sd); sd2 = wsum(sd2);
  int wid = t >> 6, lane = t & 63;
  if (lane == 0){ s1[wid] = sd; s2[wid] = sd2; }
  __syncthreads();
  if (t == 0){
    double S  = (double)s1[0] + (double)s1[1] + (double)s1[2] + (double)s1[3];
    double S2 = (double)s2[0] + (double)s2[1] + (double)s2[2] + (double)s2[3];
    atomicAdd(&sums[m*2 + 0], S);
    atomicAdd(&sums[m*2 + 1], S2);
  }
}

// K3a: selection + softmax + o-accum, no GEMM (reads precomputed D,S rows).
__global__ __launch_bounds__(256)
void k3a(const float* __restrict__ f, const float* __restrict__ Dg, const float* __restrict__ Sg,
         const float* __restrict__ baseg, float* __restrict__ out){
  __shared__ __align__(16) float Sl[4][NN];     // 16KB probs
  __shared__ float hist[4][256];                // 4KB
  __shared__ int   cand[4][32];
  __shared__ float candD[4][32];
  __shared__ int   flg[4][32];
  __shared__ int   cnt4[4];
  __shared__ int   selI4[4];
  __shared__ float selC4[4];
  __shared__ __align__(16) float opart[4][4][64]; // 4KB

  int bid = blockIdx.x;
  int tile = bid & 255;
  int q = (bid >> 8) % 9;
  int b = bid / 2304;
  int r = q / 3, s = q - 3*r; (void)r;
  int m = b*9 + q;
  int i0 = tile*4;
  int t = threadIdx.x;
  int w = t >> 6, lane = t & 63;

  const float* Drow = Dg + (size_t)m*NN*NN + (size_t)(i0+w)*NN;
  const float* Srow = Sg + (size_t)m*NN*NN + (size_t)(i0+w)*NN;

  // load D row into registers: k = 4*c2+u  ->  j = c2*256 + 4*lane + u
  float dreg[16];
  #pragma unroll
  for (int c2=0;c2<4;c2++){
    float4 v = ld4(&Drow[c2*256 + 4*lane]);
    dreg[4*c2+0]=v.x; dreg[4*c2+1]=v.y; dreg[4*c2+2]=v.z; dreg[4*c2+3]=v.w;
  }

  // row min/max
  float lmin = 3.4e38f, lmax = -3.4e38f;
  #pragma unroll
  for (int k=0;k<16;k++){ lmin = fminf(lmin,dreg[k]); lmax = fmaxf(lmax,dreg[k]); }
  float Dmin = wminr(lmin);
  float Dmax = wmaxr(lmax);

  // softmax(-D/tau) denom and probs
  float lz = 0.f;
  #pragma unroll
  for (int k=0;k<16;k++) lz += expf((Dmin - dreg[k])*0.1f);
  float Z = wsum(lz);
  float invZ = 1.0f/Z;
  float preg[16];
  #pragma unroll
  for (int k=0;k<16;k++) preg[k] = expf((Dmin - dreg[k])*0.1f)*invZ;

  // entropy / decay
  float le = 0.f;
  #pragma unroll
  for (int k=0;k<16;k++) le += preg[k]*logf(preg[k] + 1e-8f);
  float ent = -wsum(le);
  float decay = expf(-ent);

  float range = Dmax - Dmin;
  float scale1 = 256.0f / fmaxf(range, 1e-30f);

  // level 1 histogram
  #pragma unroll
  for (int i=0;i<4;i++) hist[w][lane*4+i] = 0.f;
  __syncthreads();
  #pragma unroll
  for (int k=0;k<16;k++){
    int b1 = (int)((dreg[k]-Dmin)*scale1); b1 = (b1>255)?255:b1;
    atomicAdd(&hist[w][b1], preg[k]);
  }
  __syncthreads();
  {
    float h0=hist[w][lane*4+0], h1=hist[w][lane*4+1], h2=hist[w][lane*4+2], h3=hist[w][lane*4+3];
    float tot = h0+h1+h2+h3;
    float incl = tot;
    #pragma unroll
    for (int o=1;o<64;o<<=1){ float v = __shfl_up(incl,o); if (lane>=o) incl += v; }
    float excl = incl - tot;
    float c0=excl, c1=excl+h0, c2=c1+h1, c3=c2+h2;
    if (c0<=0.8f && 0.8f<c0+h0){ selI4[w]=lane*4+0; selC4[w]=c0; }
    if (c1<=0.8f && 0.8f<c1+h1){ selI4[w]=lane*4+1; selC4[w]=c1; }
    if (c2<=0.8f && 0.8f<c2+h2){ selI4[w]=lane*4+2; selC4[w]=c2; }
    if (c3<=0.8f && 0.8f<c3+h3){ selI4[w]=lane*4+3; selC4[w]=c3; }
  }
  __syncthreads();
  int B1 = selI4[w]; float cb1 = selC4[w];
  float lo2 = Dmin + (float)B1/scale1;
  float scale2 = scale1*256.0f;

  // level 2
  #pragma unroll
  for (int i=0;i<4;i++) hist[w][lane*4+i] = 0.f;
  if (lane==0) cnt4[w] = 0;
  __syncthreads();
  #pragma unroll
  for (int k=0;k<16;k++){
    int b1 = (int)((dreg[k]-Dmin)*scale1); b1 = (b1>255)?255:b1;
    if (b1 == B1){
      int b2 = (int)((dreg[k]-lo2)*scale2); b2 = (b2<0)?0:((b2>255)?255:b2);
      atomicAdd(&hist[w][b2], preg[k]);
    }
  }
  __syncthreads();
  {
    float h0=hist[w][lane*4+0], h1=hist[w][lane*4+1], h2=hist[w][lane*4+2], h3=hist[w][lane*4+3];
    float tot = h0+h1+h2+h3;
    float incl = tot;
    #pragma unroll
    for (int o=1;o<64;o<<=1){ float v = __shfl_up(incl,o); if (lane>=o) incl += v; }
    float excl = incl - tot;
    float c0=cb1+excl, c1=c0+h0, c2=c1+h1, c3=c2+h2;
    if (c0<=0.8f && 0.8f<c0+h0){ selI4[w]=lane*4+0; selC4[w]=c0; }
    if (c1<=0.8f && 0.8f<c1+h1){ selI4[w]=lane*4+1; selC4[w]=c1; }
    if (c2<=0.8f && 0.8f<c2+h2){ selI4[w]=lane*4+2; selC4[w]=c2; }
    if (c3<=0.8f && 0.8f<c3+h3){ selI4[w]=lane*4+3; selC4[w]=c3; }
  }
  __syncthreads();
  int B2 = selI4[w]; float cb2 = selC4[w];

  // collect candidates
  #pragma unroll
  for (int k=0;k<16;k++){
    int b1 = (int)((dreg[k]-Dmin)*scale1); b1 = (b1>255)?255:b1;
    if (b1 == B1){
      int b2 = (int)((dreg[k]-lo2)*scale2); b2 = (b2<0)?0:((b2>255)?255:b2);
      if (b2 == B2){
        int c = atomicAdd(&cnt4[w], 1);
        if (c < 32){
          cand[w][c] = (k>>2)*256 + 4*lane + (k&3);
          candD[w][c] = dreg[k];
        }
      }
    }
  }
  __syncthreads();
  if (lane == 0){
    int n = cnt4[w]; n = (n>32)?32:n;
    for (int a=0;a<n;a++){
      int ja = cand[w][a]; float da = candD[w][a];
      float acc = cb2;
      for (int bb=0;bb<n;bb++){
        int jb = cand[w][bb]; float db = candD[w][bb];
        if (db < da || (db == da && jb <= ja))
          acc += expf((Dmin - db)*0.1f)*invZ;
      }
      flg[w][a] = (acc <= 0.8f) ? 1 : 0;
    }
  }
  __syncthreads();
  int ncand = cnt4[w]; ncand = (ncand>32)?32:ncand;

  // final mask + S + softmax
  float lg[16];
  #pragma unroll
  for (int c2=0;c2<4;c2++){
    float4 v = ld4(&Srow[c2*256 + 4*lane]);
    lg[4*c2+0]=v.x; lg[4*c2+1]=v.y; lg[4*c2+2]=v.z; lg[4*c2+3]=v.w;
  }
  float Tbase = baseg[m];
  float sreg[16];
  #pragma unroll
  for (int k=0;k<16;k++){
    int j = (k>>2)*256 + 4*lane + (k&3);
    float d = dreg[k];
    int b1 = (int)((d-Dmin)*scale1); b1 = (b1>255)?255:b1;
    int sel;
    if (b1 < B1) sel = 1;
    else if (b1 > B1) sel = 0;
    else {
      int b2 = (int)((d-lo2)*scale2); b2 = (b2<0)?0:((b2>255)?255:b2);
      if (b2 < B2) sel = 1;
      else if (b2 > B2) sel = 0;
      else {
        sel = 0;
        for (int c2=0;c2<ncand;c2++) if (cand[w][c2]==j) sel = flg[w][c2];
      }
    }
    float T = Tbase + 0.01f*(1.0f - d/Dmax)*decay;
    sreg[k] = (sel && (d < T)) ? lg[k] : 0.f;
  }
  float lm = -3.4e38f;
  #pragma unroll
  for (int k=0;k<16;k++) lm = fmaxf(lm, sreg[k]);
  float M = wmaxr(lm);
  float ls = 0.f;
  #pragma unroll
  for (int k=0;k<16;k++) ls += expf(sreg[k]-M);
  float Z2 = wsum(ls);
  float iZ2 = 1.0f/Z2;
  #pragma unroll
  for (int c2=0;c2<4;c2++){
    float4 v;
    v.x = expf(sreg[4*c2+0]-M)*iZ2;
    v.y = expf(sreg[4*c2+1]-M)*iZ2;
    v.z = expf(sreg[4*c2+2]-M)*iZ2;
    v.w = expf(sreg[4*c2+3]-M)*iZ2;
    *reinterpret_cast<float4*>(&Sl[w][c2*256 + 4*lane]) = v;
  }
  __syncthreads();

  // o-accum: thread (jj = t>>4, cg = t&15) handles j = jj + 16*m2, channels 4cg..4cg+3
  int cg = t & 15;
  int jj = t >> 4;
  float acc[4][4];
  #pragma unroll
  for (int rr=0;rr<4;rr++){
    #pragma unroll
    for (int i=0;i<4;i++) acc[rr][i]=0.f;
  }
  const float* fs = f + (size_t)((s*BB + b)*NN)*CC;
  for (int m2=0;m2<64;m2++){
    int j = jj + 16*m2;
    float4 fv = ld4(&fs[(size_t)j*CC + cg*4]);
    float p0 = Sl[0][j], p1 = Sl[1][j], p2 = Sl[2][j], p3 = Sl[3][j];
    acc[0][0]+=p0*fv.x; acc[0][1]+=p0*fv.y; acc[0][2]+=p0*fv.z; acc[0][3]+=p0*fv.w;
    acc[1][0]+=p1*fv.x; acc[1][1]+=p1*fv.y; acc[1][2]+=p1*fv.z; acc[1][3]+=p1*fv.w;
    acc[2][0]+=p2*fv.x; acc[2][1]+=p2*fv.y; acc[2][2]+=p2*fv.z; acc[2][3]+=p2*fv.w;
    acc[3][0]+=p3*fv.x; acc[3][1]+=p3*fv.y; acc[3][2]+=p3*fv.z; acc[3][3]+=p3*fv.w;
  }
  #pragma unroll
  for (int rr=0;rr<4;rr++){
    #pragma unroll
    for (int i=0;i<4;i++){
      acc[rr][i] += __shfl_xor(acc[rr][i], 16);
      acc[rr][i] += __shfl_xor(acc[rr][i], 32);
    }
  }
  if (lane < 16){
    #pragma unroll
    for (int rr=0;rr<4;rr++){
      float4 v; v.x=acc[rr][0]; v.y=acc[rr][1]; v.z=acc[rr][2]; v.w=acc[rr][3];
      *reinterpret_cast<float4*>(&opart[w][rr][cg*4]) = v;
    }
  }
  __syncthreads();
  {
    int rr = t >> 6, cc2 = t & 63;
    float v = opart[0][rr][cc2]+opart[1][rr][cc2]+opart[2][rr][cc2]+opart[3][rr][cc2];
    atomicAdd(&out[(size_t)(b*CC + cc2)*NN + i0 + rr], v);
  }
}

// ================= PATH B (fallback, small workspace) — proven R2 kernels =================
#define R1 16
__global__ __launch_bounds__(256)
void k1(const float* __restrict__ x1, const float* __restrict__ x2, const float* __restrict__ x3,
        const float* __restrict__ f, const float* __restrict__ fnT,
        const float* __restrict__ nrm2g, double* __restrict__ sums){
  int bid = blockIdx.x;
  int tile = bid & 63;
  int q = (bid >> 6) % 9;
  int b = bid / 576;
  int r = q / 3, s = q - 3*r;
  bool euc = (r == s);
  int i0 = tile * R1;
  int t = threadIdx.x;
  __shared__ float yl[R1][64];
  __shared__ float yn2[R1];
  __shared__ float s1[4], s2[4];
  if (t < R1) yn2[t] = nrm2g[(size_t)(r*BB + b)*NN + i0 + t];
  __syncthreads();
  for (int idx = t; idx < R1*64; idx += 256){
    int rr = idx >> 6, c = idx & 63;
    float v = f[((size_t)(r*BB + b)*NN + i0 + rr)*CC + c];
    if (!euc) v *= 1.0f / fmaxf(sqrtf(yn2[rr]), 1e-12f);
    yl[rr][c] = v;
  }
  __syncthreads();
  const float* xs = (s==0)?x1:((s==1)?x2:x3);
  const float* colD = euc ? (xs + (size_t)(b*CC)*NN) : (fnT + (size_t)((s*BB + b)*CC)*NN);
  float acc[R1][4];
  #pragma unroll
  for (int rr=0; rr<R1; rr++){
    #pragma unroll
    for (int k=0;k<4;k++) acc[rr][k] = 0.f;
  }
  for (int c=0;c<CC;c++){
    float cv[4];
    #pragma unroll
    for (int k=0;k<4;k++) cv[k] = colD[(size_t)c*NN + t + k*256];
    #pragma unroll
    for (int rr=0; rr<R1; rr++){
      float yv = yl[rr][c];
      #pragma unroll
      for (int k=0;k<4;k++) acc[rr][k] += yv*cv[k];
    }
  }
  float cn2[4];
  if (euc){
    #pragma unroll
    for (int k=0;k<4;k++) cn2[k] = nrm2g[(size_t)(s*BB + b)*NN + t + k*256];
  }
  float sd = 0.f, sd2 = 0.f;
  #pragma unroll
  for (int rr=0; rr<R1; rr++){
    #pragma unroll
    for (int k=0;k<4;k++){
      float d;
      if (euc){
        float sq = yn2[rr] + cn2[k] - 2.0f*acc[rr][k];
        d = sqrtf(fmaxf(sq, 1e-12f));
      } else {
        d = 1.0f - acc[rr][k];
      }
      sd += d; sd2 += d*d;
    }
  }
  sd = wsum(sd); sd2 = wsum(sd2);
  int wid = t >> 6, lane = t & 63;
  if (lane == 0){ s1[wid] = sd; s2[wid] = sd2; }
  __syncthreads();
  if (t == 0){
    double S  = (double)s1[0] + (double)s1[1] + (double)s1[2] + (double)s1[3];
    double S2 = (double)s2[0] + (double)s2[1] + (double)s2[2] + (double)s2[3];
    atomicAdd(&sums[(b*9 + q)*2 + 0], S);
    atomicAdd(&sums[(b*9 + q)*2 + 1], S2);
  }
}

__global__ __launch_bounds__(256, 3)
void k3(const float* __restrict__ x1, const float* __restrict__ x2, const float* __restrict__ x3,
        const float* __restrict__ f, const float* __restrict__ p,
        const float* __restrict__ fnT, const float* __restrict__ pT,
        const float* __restrict__ nrm2g, const float* __restrict__ baseg,
        float* __restrict__ out){
  __shared__ float Dl[4][NN];
  __shared__ float Sl[4][NN];
  __shared__ float hist[4][256];
  __shared__ int   cand[4][64];
  __shared__ int   flg[4][64];
  __shared__ int   cnt4[4];
  __shared__ int   selI4[4];
  __shared__ float selC4[4];
  __shared__ float yl[4][CC];
  __shared__ float pyl[4][CC];
  __shared__ float yn2[4];
  __shared__ float opart[4][4][CC];

  int bid = blockIdx.x;
  int tile = bid & 255;
  int q = (bid >> 8) % 9;
  int b = bid / 2304;
  int r = q / 3, s = q - 3*r;
  bool euc = (r == s);
  int i0 = tile * 4;
  int t = threadIdx.x;
  int w = t >> 6, lane = t & 63;

  if (t < 4) yn2[t] = nrm2g[(size_t)(r*BB + b)*NN + i0 + t];
  __syncthreads();
  for (int idx = t; idx < 4*CC; idx += 256){
    int rr = idx >> 6, c = idx & 63;
    float v = f[((size_t)(r*BB + b)*NN + i0 + rr)*CC + c];
    if (!euc) v *= 1.0f / fmaxf(sqrtf(yn2[rr]), 1e-12f);
    yl[rr][c] = v;
    pyl[rr][c] = p[((size_t)(r*BB + b)*NN + i0 + rr)*CC + c];
  }
  __syncthreads();

  const float* xs = (s==0)?x1:((s==1)?x2:x3);
  const float* colD = euc ? (xs + (size_t)(b*CC)*NN) : (fnT + (size_t)((s*BB + b)*CC)*NN);
  const float* colP = pT + (size_t)((s*BB + b)*CC)*NN;

  {
    float ad[4][4], ap[4][4];
    #pragma unroll
    for (int rr=0; rr<4; rr++){
      #pragma unroll
      for (int k=0;k<4;k++){ ad[rr][k]=0.f; ap[rr][k]=0.f; }
    }
    for (int c=0;c<CC;c++){
      float cvd[4], cvp[4];
      #pragma unroll
      for (int k=0;k<4;k++){
        cvd[k] = colD[(size_t)c*NN + t + k*256];
        cvp[k] = colP[(size_t)c*NN + t + k*256];
      }
      #pragma unroll
      for (int rr=0;rr<4;rr++){
        float yv = yl[rr][c], pv = pyl[rr][c];
        #pragma unroll
        for (int k=0;k<4;k++){ ad[rr][k] += yv*cvd[k]; ap[rr][k] += pv*cvp[k]; }
      }
    }
    if (euc){
      float cn2[4];
      #pragma unroll
      for (int k=0;k<4;k++) cn2[k] = nrm2g[(size_t)(s*BB + b)*NN + t + k*256];
      #pragma unroll
      for (int rr=0;rr<4;rr++){
        #pragma unroll
        for (int k=0;k<4;k++){
          float sq = yn2[rr] + cn2[k] - 2.0f*ad[rr][k];
          Dl[rr][t + k*256] = sqrtf(fmaxf(sq, 1e-12f));
          Sl[rr][t + k*256] = ap[rr][k];
        }
      }
    } else {
      #pragma unroll
      for (int rr=0;rr<4;rr++){
        #pragma unroll
        for (int k=0;k<4;k++){
          Dl[rr][t + k*256] = 1.0f - ad[rr][k];
          Sl[rr][t + k*256] = ap[rr][k];
        }
      }
    }
  }
  __syncthreads();

  float Tbase = baseg[b*9 + q];

  float dreg[16], preg[16];
  #pragma unroll
  for (int k=0;k<16;k++) dreg[k] = Dl[w][lane + 64*k];

  float lmin = 3.4e38f, lmax = -3.4e38f;
  #pragma unroll
  for (int k=0;k<16;k++){ lmin = fminf(lmin,dreg[k]); lmax = fmaxf(lmax,dreg[k]); }
  float Dmin = wminr(lmin);
  float Dmax = wmaxr(lmax);

  float lz = 0.f;
  #pragma unroll
  for (int k=0;k<16;k++) lz += expf((Dmin - dreg[k])*0.1f);
  float Z = wsum(lz);
  float invZ = 1.0f/Z;
  #pragma unroll
  for (int k=0;k<16;k++) preg[k] = expf((Dmin - dreg[k])*0.1f)*invZ;

  float le = 0.f;
  #pragma unroll
  for (int k=0;k<16;k++) le += preg[k]*logf(preg[k] + 1e-8f);
  float ent = -wsum(le);
  float decay = expf(-ent);

  float range = Dmax - Dmin;
  float scale1 = 256.0f / fmaxf(range, 1e-30f);

  #pragma unroll
  for (int i=0;i<4;i++) hist[w][lane*4+i] = 0.f;
  __syncthreads();
  #pragma unroll
  for (int k=0;k<16;k++){
    int b1 = (int)((dreg[k]-Dmin)*scale1); b1 = (b1>255)?255:b1;
    atomicAdd(&hist[w][b1], preg[k]);
  }
  __syncthreads();
  {
    float h0=hist[w][lane*4+0], h1=hist[w][lane*4+1], h2=hist[w][lane*4+2], h3=hist[w][lane*4+3];
    float tot = h0+h1+h2+h3;
    float incl = tot;
    #pragma unroll
    for (int o=1;o<64;o<<=1){ float v = __shfl_up(incl,o); if (lane>=o) incl += v; }
    float excl = incl - tot;
    float c0=excl, c1=excl+h0, c2=c1+h1, c3=c2+h2;
    if (c0<=0.8f && 0.8f<c0+h0){ selI4[w]=lane*4+0; selC4[w]=c0; }
    if (c1<=0.8f && 0.8f<c1+h1){ selI4[w]=lane*4+1; selC4[w]=c1; }
    if (c2<=0.8f && 0.8f<c2+h2){ selI4[w]=lane*4+2; selC4[w]=c2; }
    if (c3<=0.8f && 0.8f<c3+h3){ selI4[w]=lane*4+3; selC4[w]=c3; }
  }
  __syncthreads();
  int B1 = selI4[w]; float cb1 = selC4[w];
  float lo2 = Dmin + (float)B1/scale1;
  float scale2 = scale1*256.0f;

  #pragma unroll
  for (int i=0;i<4;i++) hist[w][lane*4+i] = 0.f;
  if (lane==0) cnt4[w] = 0;
  __syncthreads();
  #pragma unroll
  for (int k=0;k<16;k++){
    int b1 = (int)((dreg[k]-Dmin)*scale1); b1 = (b1>255)?255:b1;
    if (b1 == B1){
      int b2 = (int)((dreg[k]-lo2)*scale2); b2 = (b2<0)?0:((b2>255)?255:b2);
      atomicAdd(&hist[w][b2], preg[k]);
    }
  }
  __syncthreads();
  {
    float h0=hist[w][lane*4+0], h1=hist[w][lane*4+1], h2=hist[w][lane*4+2], h3=hist[w][lane*4+3];
    float tot = h0+h1+h2+h3;
    float incl = tot;
    #pragma unroll
    for (int o=1;o<64;o<<=1){ float v = __shfl_up(incl,o); if (lane>=o) incl += v; }
    float excl = incl - tot;
    float c0=cb1+excl, c1=c0+h0, c2=c1+h1, c3=c2+h2;
    if (c0<=0.8f && 0.8f<c0+h0){ selI4[w]=lane*4+0; selC4[w]=c0; }
    if (c1<=0.8f && 0.8f<c1+h1){ selI4[w]=lane*4+1; selC4[w]=c1; }
    if (c2<=0.8f && 0.8f<c2+h2){ selI4[w]=lane*4+2; selC4[w]=c2; }
    if (c3<=0.8f && 0.8f<c3+h3){ selI4[w]=lane*4+3; selC4[w]=c3; }
  }
  __syncthreads();
  int B2 = selI4[w]; float cb2 = selC4[w];

  #pragma unroll
  for (int k=0;k<16;k++){
    int b1 = (int)((dreg[k]-Dmin)*scale1); b1 = (b1>255)?255:b1;
    if (b1 == B1){
      int b2 = (int)((dreg[k]-lo2)*scale2); b2 = (b2<0)?0:((b2>255)?255:b2);
      if (b2 == B2){
        int c = atomicAdd(&cnt4[w], 1);
        if (c < 64) cand[w][c] = lane + 64*k;
      }
    }
  }
  __syncthreads();
  if (lane == 0){
    int n = cnt4[w]; n = (n>64)?64:n;
    for (int a=0;a<n;a++){
      int ja = cand[w][a]; float da = Dl[w][ja];
      float acc = cb2;
      for (int bb=0;bb<n;bb++){
        int jb = cand[w][bb]; float db = Dl[w][jb];
        if (db < da || (db == da && jb <= ja))
          acc += expf((Dmin - db)*0.1f)*invZ;
      }
      flg[w][a] = (acc <= 0.8f) ? 1 : 0;
    }
  }
  __syncthreads();
  int ncand = cnt4[w]; ncand = (ncand>64)?64:ncand;

  float sreg[16];
  #pragma unroll
  for (int k=0;k<16;k++){
    int j = lane + 64*k;
    float d = dreg[k];
    int b1 = (int)((d-Dmin)*scale1); b1 = (b1>255)?255:b1;
    int sel;
    if (b1 < B1) sel = 1;
    else if (b1 > B1) sel = 0;
    else {
      int b2 = (int)((d-lo2)*scale2); b2 = (b2<0)?0:((b2>255)?255:b2);
      if (b2 < B2) sel = 1;
      else if (b2 > B2) sel = 0;
      else {
        sel = 0;
        for (int c2=0;c2<ncand;c2++) if (cand[w][c2]==j) sel = flg[w][c2];
      }
    }
    float T = Tbase + 0.01f*(1.0f - d/Dmax)*decay;
    sreg[k] = (sel && (d < T)) ? Sl[w][j] : 0.f;
  }
  float lm = -3.4e38f;
  #pragma unroll
  for (int k=0;k<16;k++) lm = fmaxf(lm, sreg[k]);
  float M = wmaxr(lm);
  float ls = 0.f;
  #pragma unroll
  for (int k=0;k<16;k++) ls += expf(sreg[k]-M);
  float Z2 = wsum(ls);
  float iZ2 = 1.0f/Z2;
  #pragma unroll
  for (int k=0;k<16;k++) Sl[w][lane + 64*k] = expf(sreg[k]-M)*iZ2;
  __syncthreads();

  const float* fs = f + (size_t)((s*BB + b)*NN)*CC;
  int g = t >> 6, c = t & 63;
  float ov0=0.f, ov1=0.f, ov2=0.f, ov3=0.f;
  int j0 = g*256;
  for (int j = j0; j < j0+256; j++){
    float fv = fs[(size_t)j*CC + c];
    ov0 += Sl[0][j]*fv;
    ov1 += Sl[1][j]*fv;
    ov2 += Sl[2][j]*fv;
    ov3 += Sl[3][j]*fv;
  }
  opart[g][0][c]=ov0; opart[g][1][c]=ov1; opart[g][2][c]=ov2; opart[g][3][c]=ov3;
  __syncthreads();
  {
    int rr = t >> 6, cc2 = t & 63;
    float v = opart[0][rr][cc2]+opart[1][rr][cc2]+opart[2][rr][cc2]+opart[3][rr][cc2];
    atomicAdd(&out[(size_t)(b*CC + cc2)*NN + i0 + rr], v);
  }
}

extern "C" void kernel_launch(void* const* d_in, const int* in_sizes, int n_in,
                              void* d_out, int out_size, void* d_ws, size_t ws_size,
                              hipStream_t stream){
  const float* x1 = (const float*)d_in[0];
  const float* x2 = (const float*)d_in[1];
  const float* x3 = (const float*)d_in[2];
  const float* w1 = (const float*)d_in[3];
  const float* b1 = (const float*)d_in[4];
  const float* w2 = (const float*)d_in[5];
  const float* b2 = (const float*)d_in[6];
  const float* w3 = (const float*)d_in[7];
  const float* b3 = (const float*)d_in[8];

  char* ws = (char*)d_ws;
  const size_t SZ = (size_t)3*BB*NN*CC*sizeof(float);   // 1.5MB each
  float*  f    = (float*)(ws);
  float*  p    = (float*)(ws + SZ);
  float*  fnT  = (float*)(ws + 2*SZ);
  float*  pT   = (float*)(ws + 3*SZ);
  float*  nrm2 = (float*)(ws + 4*SZ);
  double* sums = (double*)(ws + 4*SZ + 32768);
  float*  baseg= (float*)(ws + 4*SZ + 32768 + 512);

  const size_t MATS = (size_t)18*NN*NN*sizeof(float);   // 72MB
  const size_t BIG0 = (size_t)8*1024*1024;
  float* Dg = (float*)(ws + BIG0);
  float* Sg = (float*)(ws + BIG0 + MATS);
  bool big = ws_size >= BIG0 + 2*MATS;

  float* out = (float*)d_out;

  kz <<<512, 256, 0, stream>>>(out, sums);
  k0a<<<96,  256, 0, stream>>>(x1, x2, x3, f);
  k0b<<<384, 256, 0, stream>>>(f, w1, b1, w2, b2, w3, b3, p, pT, fnT, nrm2);
  if (big){
    k1a<<<2304,256, 0, stream>>>(x1, x2, x3, f, p, fnT, pT, nrm2, sums, Dg, Sg);
    k2 <<<1,   64,  0, stream>>>(sums, baseg);
    k3a<<<4608,256, 0, stream>>>(f, Dg, Sg, baseg, out);
  } else {
    k1 <<<1152,256, 0, stream>>>(x1, x2, x3, f, fnT, nrm2, sums);
    k2 <<<1,   64,  0, stream>>>(sums, baseg);
    k3 <<<4608,256, 0, stream>>>(x1, x2, x3, f, p, fnT, pT, nrm2, baseg, out);
  }
}